// Round 2
// baseline (4343.102 us; speedup 1.0000x reference)
//
#include <hip/hip_runtime.h>
#include <hip/hip_bf16.h>

#define N_NODES 100000

typedef unsigned short ushort_t;

// ---------------- helpers ----------------
__device__ inline float bfbits2f(unsigned int lo16) { return __uint_as_float(lo16 << 16); }

__device__ inline ushort_t f2bfbits(float f) {
    __hip_bfloat16 h = __float2bfloat16(f);
    return *reinterpret_cast<ushort_t*>(&h);
}

// load 8 consecutive elements as float
__device__ inline void load8(const float* __restrict__ p, float* v) {
    float4 u0 = *(const float4*)p;
    float4 u1 = *(const float4*)(p + 4);
    v[0] = u0.x; v[1] = u0.y; v[2] = u0.z; v[3] = u0.w;
    v[4] = u1.x; v[5] = u1.y; v[6] = u1.z; v[7] = u1.w;
}
__device__ inline void load8(const __hip_bfloat16* __restrict__ p, float* v) {
    uint4 u = *(const uint4*)p;  // 8 bf16
    v[0] = bfbits2f(u.x & 0xffffu); v[1] = __uint_as_float(u.x & 0xffff0000u);
    v[2] = bfbits2f(u.y & 0xffffu); v[3] = __uint_as_float(u.y & 0xffff0000u);
    v[4] = bfbits2f(u.z & 0xffffu); v[5] = __uint_as_float(u.z & 0xffff0000u);
    v[6] = bfbits2f(u.w & 0xffffu); v[7] = __uint_as_float(u.w & 0xffff0000u);
}

// ---------------- degree count ----------------
__global__ void count_kernel(const int* __restrict__ dst, float* __restrict__ cnt, int E) {
    int e = blockIdx.x * blockDim.x + threadIdx.x;
    if (e < E) {
        unsigned d = (unsigned)dst[e];
        if (d < N_NODES) unsafeAtomicAdd(&cnt[d], 1.0f);
    }
}

__global__ void inv_kernel(float* __restrict__ cnt, int n) {
    int i = blockIdx.x * blockDim.x + threadIdx.x;
    if (i < n) cnt[i] = 1.0f / fmaxf(cnt[i], 1.0f);
}

// ---------------- edge scatter-add over a CW-wide f32 chunk ----------------
template <int CW>
__global__ void scatter_add(const float* __restrict__ Y, const int* __restrict__ src,
                            const int* __restrict__ dst, float* __restrict__ S, int E) {
    if (CW == 64) {
        const int lane = threadIdx.x & 63;
        int wid = (blockIdx.x * blockDim.x + threadIdx.x) >> 6;
        const int nw = (gridDim.x * blockDim.x) >> 6;
        for (int e = wid; e < E; e += nw) {
            unsigned s = (unsigned)src[e], d = (unsigned)dst[e];
            if (s >= N_NODES || d >= N_NODES) continue;
            unsafeAtomicAdd(&S[(size_t)d * 64 + lane], Y[(size_t)s * 64 + lane]);
        }
    } else {  // CW == 32: each half-wave handles an edge
        const int lane = threadIdx.x & 31;
        int hw = (blockIdx.x * blockDim.x + threadIdx.x) >> 5;
        const int nh = (gridDim.x * blockDim.x) >> 5;
        for (int e = hw; e < E; e += nh) {
            unsigned s = (unsigned)src[e], d = (unsigned)dst[e];
            if (s >= N_NODES || d >= N_NODES) continue;
            unsafeAtomicAdd(&S[(size_t)d * 32 + lane], Y[(size_t)s * 32 + lane]);
        }
    }
}

// ---------------- GEMM over a CW-wide column slice of W ----------------
// out[n][out_col0+jj] = (opt relu)( sum_k A[n][k] * W[k][j0+jj]  (+ S[n][jj]*inv[n] + b[j0+jj]) )
// A: [N x K] (float or bf16), W: [K x J] row-major, slice cols [j0, j0+BN)
template <typename AT, int K, int BN, bool ADD_S, bool RELU, typename OT>
__global__ __launch_bounds__(256) void sage_gemm(const AT* __restrict__ A,
                                                 const float* __restrict__ W, int J, int j0,
                                                 const float* __restrict__ S,
                                                 const float* __restrict__ inv,
                                                 const float* __restrict__ b,
                                                 OT* __restrict__ out, int out_ld, int out_col0) {
    constexpr int BM = 64, BK = 32;
    constexpr int MC = BN / 16;  // cols per thread (4 or 2)
    __shared__ float As[BK][BM + 4];
    __shared__ float Bs[BK][BN + 4];

    const int t = threadIdx.x;
    const int n0 = blockIdx.x * BM;
    const int tm = t & 15;   // row micro-group
    const int tj = t >> 4;   // col micro-group (0..15)

    const int a_m = t >> 2;          // 0..63
    const int a_k = (t & 3) * 8;     // 0,8,16,24
    const int an = n0 + a_m;
    const bool a_ok = (an < N_NODES);

    float acc[4][MC] = {};

    for (int k0 = 0; k0 < K; k0 += BK) {
        // ---- stage A ----
        {
            float v[8];
            if (a_ok) load8(A + (size_t)an * K + k0 + a_k, v);
            else
#pragma unroll
                for (int i = 0; i < 8; ++i) v[i] = 0.0f;
#pragma unroll
            for (int i = 0; i < 8; ++i) As[a_k + i][a_m] = v[i];
        }
        // ---- stage B slice ----
        if (BN == 64) {
            const int b_k = t >> 3, b_j = (t & 7) * 8;
            const float* wr = W + (size_t)(k0 + b_k) * J + j0 + b_j;
            *(float4*)&Bs[b_k][b_j] = *(const float4*)wr;
            *(float4*)&Bs[b_k][b_j + 4] = *(const float4*)(wr + 4);
        } else {  // BN == 32
            const int b_k = t >> 3, b_j = (t & 7) * 4;
            const float* wr = W + (size_t)(k0 + b_k) * J + j0 + b_j;
            *(float4*)&Bs[b_k][b_j] = *(const float4*)wr;
        }
        __syncthreads();

#pragma unroll
        for (int k = 0; k < BK; ++k) {
            float4 a4 = *(const float4*)&As[k][tm * 4];
            float av[4] = {a4.x, a4.y, a4.z, a4.w};
            float bv[MC];
            if (MC == 4) {
                float4 b4 = *(const float4*)&Bs[k][tj * 4];
                bv[0] = b4.x; bv[1] = b4.y; bv[2] = b4.z; bv[3] = b4.w;
            } else {
                float2 b2 = *(const float2*)&Bs[k][tj * 2];
                bv[0] = b2.x; bv[1] = b2.y;
            }
#pragma unroll
            for (int mi = 0; mi < 4; ++mi)
#pragma unroll
                for (int ci = 0; ci < MC; ++ci) acc[mi][ci] += av[mi] * bv[ci];
        }
        __syncthreads();
    }

    // ---- epilogue ----
    const int jj = tj * MC;  // col within chunk
    float bb[MC];
#pragma unroll
    for (int ci = 0; ci < MC; ++ci) bb[ci] = ADD_S ? b[j0 + jj + ci] : 0.0f;

#pragma unroll
    for (int mi = 0; mi < 4; ++mi) {
        const int n = n0 + tm * 4 + mi;
        if (n >= N_NODES) continue;
        float o[MC];
        if (ADD_S) {
            const float iv = inv[n];
#pragma unroll
            for (int ci = 0; ci < MC; ++ci)
                o[ci] = acc[mi][ci] + S[(size_t)n * BN + jj + ci] * iv + bb[ci];
        } else {
#pragma unroll
            for (int ci = 0; ci < MC; ++ci) o[ci] = acc[mi][ci];
        }
        if (RELU) {
#pragma unroll
            for (int ci = 0; ci < MC; ++ci) o[ci] = fmaxf(o[ci], 0.0f);
        }
        OT* op = out + (size_t)n * out_ld + out_col0 + jj;
        if constexpr (sizeof(OT) == 4) {  // float out
            if (MC == 4) {
                float4 st = {o[0], o[1], o[2], o[3]};
                *(float4*)op = st;
            } else {
                float2 st = {o[0], o[1]};
                *(float2*)op = st;
            }
        } else {  // bf16 out
            if (MC == 4) {
                ushort4 st = {f2bfbits(o[0]), f2bfbits(o[1]), f2bfbits(o[2]), f2bfbits(o[3])};
                *(ushort4*)op = st;
            } else {
                ushort2 st = {f2bfbits(o[0]), f2bfbits(o[1])};
                *(ushort2*)op = st;
            }
        }
    }
}

// ---------------- host-side layer driver ----------------
template <int CW, typename AT, int K, typename OT>
static void run_layer(const AT* A, const float* Wl, const float* Wr, const float* bias, int J,
                      OT* out, float* Y, float* S, const float* inv, const int* src,
                      const int* dst, int E, hipStream_t stream) {
    const int GB = (N_NODES + 63) / 64;
    for (int j0 = 0; j0 < J; j0 += CW) {
        sage_gemm<AT, K, CW, false, false, float>
            <<<GB, 256, 0, stream>>>(A, Wl, J, j0, nullptr, nullptr, nullptr, Y, CW, 0);
        hipMemsetAsync(S, 0, (size_t)N_NODES * CW * 4, stream);
        scatter_add<CW><<<4096, 256, 0, stream>>>(Y, src, dst, S, E);
        sage_gemm<AT, K, CW, true, true, OT>
            <<<GB, 256, 0, stream>>>(A, Wr, J, j0, S, inv, bias, out, J, j0);
    }
}

template <int CW>
static void run_all(void* const* d_in, const int* in_sizes, void* d_out, void* d_ws,
                    hipStream_t stream) {
    const float* x = (const float*)d_in[0];
    const int* ei = (const int*)d_in[1];
    const float* Wl1 = (const float*)d_in[2];
    const float* Wr1 = (const float*)d_in[3];
    const float* b1 = (const float*)d_in[4];
    const float* Wl2 = (const float*)d_in[5];
    const float* Wr2 = (const float*)d_in[6];
    const float* b2 = (const float*)d_in[7];
    const float* Wl3 = (const float*)d_in[8];
    const float* Wr3 = (const float*)d_in[9];
    const float* b3 = (const float*)d_in[10];

    const int E = in_sizes[1] / 2;
    const int* src = ei;
    const int* dst = ei + E;
    const int N = N_NODES;

    char* ws = (char*)d_ws;
    float* cnt = (float*)ws;                                        // N f32
    __hip_bfloat16* h1 = (__hip_bfloat16*)(ws + (1 << 20));         // N x 256 bf16
    __hip_bfloat16* h2 = (__hip_bfloat16*)(ws + (1 << 20) + 51200000L);
    float* Y = (float*)(ws + (1 << 20) + 2 * 51200000L);            // N x CW f32
    float* S = (float*)(ws + (1 << 20) + 2 * 51200000L + (size_t)N * CW * 4);

    hipMemsetAsync(cnt, 0, (size_t)N * 4, stream);
    count_kernel<<<(E + 255) / 256, 256, 0, stream>>>(dst, cnt, E);
    inv_kernel<<<(N + 255) / 256, 256, 0, stream>>>(cnt, N);

    run_layer<CW, float, 128, __hip_bfloat16>(x, Wl1, Wr1, b1, 256, h1, Y, S, cnt, src, dst, E, stream);
    run_layer<CW, __hip_bfloat16, 256, __hip_bfloat16>(h1, Wl2, Wr2, b2, 256, h2, Y, S, cnt, src, dst, E, stream);
    run_layer<CW, __hip_bfloat16, 256, float>(h2, Wl3, Wr3, b3, 128, (float*)d_out, Y, S, cnt, src, dst, E, stream);
}

extern "C" void kernel_launch(void* const* d_in, const int* in_sizes, int n_in,
                              void* d_out, int out_size, void* d_ws, size_t ws_size,
                              hipStream_t stream) {
    const size_t base = (1 << 20) + 2 * 51200000UL;            // cnt + h1 + h2
    const size_t need64 = base + 2 * (size_t)N_NODES * 64 * 4; // + Y + S
    const size_t need32 = base + 2 * (size_t)N_NODES * 32 * 4;

    if (ws_size >= need64) {
        run_all<64>(d_in, in_sizes, d_out, d_ws, stream);
    } else if (ws_size >= need32) {
        run_all<32>(d_in, in_sizes, d_out, d_ws, stream);
    }
    // else: insufficient workspace — leave d_out untouched (clean diagnostic failure)
}

// Round 3
// 1548.595 us; speedup vs baseline: 2.8045x; 2.8045x over previous
//
#include <hip/hip_runtime.h>
#include <hip/hip_bf16.h>

#define N_NODES 100000

typedef unsigned short ushort_t;

// ---------------- helpers ----------------
__device__ inline float bfbits2f(unsigned int lo16) { return __uint_as_float(lo16 << 16); }

__device__ inline ushort_t f2bfbits(float f) {
    __hip_bfloat16 h = __float2bfloat16(f);
    return *reinterpret_cast<ushort_t*>(&h);
}

__device__ inline void load8(const float* __restrict__ p, float* v) {
    float4 u0 = *(const float4*)p;
    float4 u1 = *(const float4*)(p + 4);
    v[0] = u0.x; v[1] = u0.y; v[2] = u0.z; v[3] = u0.w;
    v[4] = u1.x; v[5] = u1.y; v[6] = u1.z; v[7] = u1.w;
}
__device__ inline void load8(const __hip_bfloat16* __restrict__ p, float* v) {
    uint4 u = *(const uint4*)p;  // 8 bf16
    v[0] = bfbits2f(u.x & 0xffffu); v[1] = __uint_as_float(u.x & 0xffff0000u);
    v[2] = bfbits2f(u.y & 0xffffu); v[3] = __uint_as_float(u.y & 0xffff0000u);
    v[4] = bfbits2f(u.z & 0xffffu); v[5] = __uint_as_float(u.z & 0xffff0000u);
    v[6] = bfbits2f(u.w & 0xffffu); v[7] = __uint_as_float(u.w & 0xffff0000u);
}

// ---------------- degree count (int) ----------------
__global__ void count_int(const int* __restrict__ dst, int* __restrict__ cnt, int E) {
    int e = blockIdx.x * blockDim.x + threadIdx.x;
    if (e < E) {
        unsigned d = (unsigned)dst[e];
        if (d < N_NODES) atomicAdd(&cnt[d], 1);
    }
}

__global__ void inv_from_cnt(const int* __restrict__ cnt, float* __restrict__ invd, int n) {
    int i = blockIdx.x * blockDim.x + threadIdx.x;
    if (i < n) invd[i] = 1.0f / (float)max(cnt[i], 1);
}

// ---------------- exclusive scan (3 kernels) ----------------
__global__ __launch_bounds__(256) void scan1(const int* __restrict__ in, int* __restrict__ out,
                                             int* __restrict__ bsum, int n) {
    __shared__ int lds[256];
    const int t = threadIdx.x;
    const int base = blockIdx.x * 1024 + t * 4;
    int4 v = {0, 0, 0, 0};
    if (base + 3 < n) v = *(const int4*)(in + base);
    else {
        v.x = (base + 0 < n) ? in[base + 0] : 0;
        v.y = (base + 1 < n) ? in[base + 1] : 0;
        v.z = (base + 2 < n) ? in[base + 2] : 0;
        v.w = (base + 3 < n) ? in[base + 3] : 0;
    }
    int s0 = v.x, s1 = s0 + v.y, s2 = s1 + v.z, s3 = s2 + v.w;  // inclusive within thread
    lds[t] = s3;
    __syncthreads();
    for (int off = 1; off < 256; off <<= 1) {
        int a = (t >= off) ? lds[t - off] : 0;
        __syncthreads();
        lds[t] += a;
        __syncthreads();
    }
    const int texcl = lds[t] - s3;
    if (t == 255) bsum[blockIdx.x] = lds[255];
    if (base + 0 < n) out[base + 0] = texcl;
    if (base + 1 < n) out[base + 1] = texcl + s0;
    if (base + 2 < n) out[base + 2] = texcl + s1;
    if (base + 3 < n) out[base + 3] = texcl + s2;
}

__global__ __launch_bounds__(256) void scan2(int* __restrict__ bsum, int nb) {
    __shared__ int lds[256];
    const int t = threadIdx.x;
    int v = (t < nb) ? bsum[t] : 0;
    lds[t] = v;
    __syncthreads();
    for (int off = 1; off < 256; off <<= 1) {
        int a = (t >= off) ? lds[t - off] : 0;
        __syncthreads();
        lds[t] += a;
        __syncthreads();
    }
    if (t < nb) bsum[t] = lds[t] - v;  // exclusive
}

__global__ void scan3(int* __restrict__ out, const int* __restrict__ bsum, int n, int E) {
    int i = blockIdx.x * blockDim.x + threadIdx.x;
    if (i < n) out[i] += bsum[i >> 10];
    if (i == 0) out[n] = E;
}

__global__ void copy_int(const int* __restrict__ a, int* __restrict__ b, int n) {
    int i = blockIdx.x * blockDim.x + threadIdx.x;
    if (i < n) b[i] = a[i];
}

// ---------------- reorder: bucket src by dst ----------------
__global__ void reorder(const int* __restrict__ src, const int* __restrict__ dst,
                        int* __restrict__ woff, int* __restrict__ csr, int E) {
    int e = blockIdx.x * blockDim.x + threadIdx.x;
    if (e < E) {
        unsigned d = (unsigned)dst[e], s = (unsigned)src[e];
        if (d < N_NODES && s < N_NODES) {
            int p = atomicAdd(&woff[d], 1);
            csr[p] = (int)s;
        }
    }
}

// ---------------- round f32 -> bf16 ----------------
__global__ void round_bf16(const float* __restrict__ x, ushort_t* __restrict__ xb, long n) {
    long i = ((long)blockIdx.x * blockDim.x + threadIdx.x) * 4;
    if (i < n) {
        float4 v = *(const float4*)(x + i);
        ushort4 o = {f2bfbits(v.x), f2bfbits(v.y), f2bfbits(v.z), f2bfbits(v.w)};
        *(ushort4*)(xb + i) = o;
    }
}

// ---------------- gather-mean: one wave per node, 128 bf16 cols ----------------
// out[n][col0 + c] = inv[n] * sum_{e in row n} Y[csr[e]][c],  c in [0,128)
template <typename OT>
__global__ __launch_bounds__(256) void gather_mean(const ushort_t* __restrict__ Y,
                                                   const int* __restrict__ roff,
                                                   const int* __restrict__ csr,
                                                   const float* __restrict__ invd,
                                                   OT* __restrict__ out, int out_ld, int col0) {
    const int w = (blockIdx.x * blockDim.x + threadIdx.x) >> 6;  // node
    const int lane = threadIdx.x & 63;
    if (w >= N_NODES) return;
    const int e0 = roff[w], e1 = roff[w + 1];
    const unsigned int* yp = (const unsigned int*)Y;  // row = 64 uints (128 bf16)
    float a0 = 0.0f, a1 = 0.0f;
    int s = (e0 < e1) ? csr[e0] : 0;
    for (int e = e0; e < e1; ++e) {
        int sn = (e + 1 < e1) ? csr[e + 1] : 0;
        unsigned int u = yp[(size_t)s * 64 + lane];
        a0 += bfbits2f(u & 0xffffu);
        a1 += __uint_as_float(u & 0xffff0000u);
        s = sn;
    }
    const float iv = invd[w];
    a0 *= iv; a1 *= iv;
    if constexpr (sizeof(OT) == 4) {  // float out
        float2 st = {a0, a1};
        *(float2*)((float*)out + (size_t)w * out_ld + col0 + lane * 2) = st;
    } else {  // bf16 out
        ushort2 st = {f2bfbits(a0), f2bfbits(a1)};
        *(ushort2*)((ushort_t*)out + (size_t)w * out_ld + col0 + lane * 2) = st;
    }
}

// ---------------- GEMM: 64x64 tile, 256 thr, 4x4 micro ----------------
// CONCAT: KTOT=2*KH, A (bf16, stride KH) for k<KH, A2 (f32, stride KH) for k>=KH;
//         W1 rows for k<KH, W2 rows for k>=KH.
// EPI:    out[n][oc+jj] = relu(out[n][oc+jj] + acc + bias)
// BR = CONCAT||EPI: bias+relu applied.
template <int KH, bool CONCAT, bool EPI, typename OT>
__global__ __launch_bounds__(256) void gemm64(const __hip_bfloat16* __restrict__ A,
                                              const float* __restrict__ A2,
                                              const float* __restrict__ W1,
                                              const float* __restrict__ W2, int J, int j0,
                                              const float* __restrict__ bias,
                                              OT* __restrict__ out, int out_ld, int ocol0) {
    constexpr int BM = 64, BK = 32;
    constexpr int KTOT = CONCAT ? 2 * KH : KH;
    constexpr bool BR = CONCAT || EPI;
    __shared__ float As[BK][BM + 4];
    __shared__ float Bs[BK][64 + 4];

    const int t = threadIdx.x;
    const int n0 = blockIdx.x * BM;
    const int jb = j0 + blockIdx.y * 64;   // W col base
    const int oc = ocol0 + blockIdx.y * 64; // out col base
    const int tm = t & 15;
    const int tj = t >> 4;

    const int a_m = t >> 2;
    const int a_k = (t & 3) * 8;
    const int an = n0 + a_m;
    const bool a_ok = (an < N_NODES);

    float acc[4][4] = {};

    for (int k0 = 0; k0 < KTOT; k0 += BK) {
        {
            const int kg = k0 + a_k;
            float v[8];
            if (a_ok) {
                if (CONCAT && kg >= KH) load8(A2 + (size_t)an * KH + (kg - KH), v);
                else load8(A + (size_t)an * KH + kg, v);
            } else {
#pragma unroll
                for (int i = 0; i < 8; ++i) v[i] = 0.0f;
            }
#pragma unroll
            for (int i = 0; i < 8; ++i) As[a_k + i][a_m] = v[i];
        }
        {
            const int b_k = t >> 3, b_j = (t & 7) * 8;
            const int kg = k0 + b_k;
            const float* wr = (CONCAT && kg >= KH) ? (W2 + (size_t)(kg - KH) * J)
                                                   : (W1 + (size_t)kg * J);
            wr += jb + b_j;
            *(float4*)&Bs[b_k][b_j] = *(const float4*)wr;
            *(float4*)&Bs[b_k][b_j + 4] = *(const float4*)(wr + 4);
        }
        __syncthreads();

#pragma unroll
        for (int k = 0; k < BK; ++k) {
            float4 a4 = *(const float4*)&As[k][tm * 4];
            float4 b4 = *(const float4*)&Bs[k][tj * 4];
            float av[4] = {a4.x, a4.y, a4.z, a4.w};
            float bv[4] = {b4.x, b4.y, b4.z, b4.w};
#pragma unroll
            for (int mi = 0; mi < 4; ++mi)
#pragma unroll
                for (int ji = 0; ji < 4; ++ji) acc[mi][ji] += av[mi] * bv[ji];
        }
        __syncthreads();
    }

    const int jj = tj * 4;
    float bb[4] = {0, 0, 0, 0};
    if (BR) {
#pragma unroll
        for (int ci = 0; ci < 4; ++ci) bb[ci] = bias[jb + jj + ci];
    }

#pragma unroll
    for (int mi = 0; mi < 4; ++mi) {
        const int n = n0 + tm * 4 + mi;
        if (n >= N_NODES) continue;
        OT* op = out + (size_t)n * out_ld + oc + jj;
        float o[4];
#pragma unroll
        for (int ci = 0; ci < 4; ++ci) o[ci] = acc[mi][ci];
        if (EPI) {
            if constexpr (sizeof(OT) == 4) {
                float4 sv = *(const float4*)op;
                o[0] += sv.x; o[1] += sv.y; o[2] += sv.z; o[3] += sv.w;
            } else {
                ushort4 su = *(const ushort4*)op;
                o[0] += bfbits2f(su.x); o[1] += bfbits2f(su.y);
                o[2] += bfbits2f(su.z); o[3] += bfbits2f(su.w);
            }
        }
        if (BR) {
#pragma unroll
            for (int ci = 0; ci < 4; ++ci) o[ci] = fmaxf(o[ci] + bb[ci], 0.0f);
        }
        if constexpr (sizeof(OT) == 4) {
            float4 st = {o[0], o[1], o[2], o[3]};
            *(float4*)op = st;
        } else {
            ushort4 st = {f2bfbits(o[0]), f2bfbits(o[1]), f2bfbits(o[2]), f2bfbits(o[3])};
            *(ushort4*)op = st;
        }
    }
}

// ---------------- launch ----------------
extern "C" void kernel_launch(void* const* d_in, const int* in_sizes, int n_in,
                              void* d_out, int out_size, void* d_ws, size_t ws_size,
                              hipStream_t stream) {
    const float* x   = (const float*)d_in[0];
    const int*   ei  = (const int*)d_in[1];
    const float* Wl1 = (const float*)d_in[2];
    const float* Wr1 = (const float*)d_in[3];
    const float* b1  = (const float*)d_in[4];
    const float* Wl2 = (const float*)d_in[5];
    const float* Wr2 = (const float*)d_in[6];
    const float* b2  = (const float*)d_in[7];
    const float* Wl3 = (const float*)d_in[8];
    const float* Wr3 = (const float*)d_in[9];
    const float* b3  = (const float*)d_in[10];

    const int E = in_sizes[1] / 2;
    const int* src = ei;
    const int* dst = ei + E;
    const int N = N_NODES;

    // ---- workspace arena (total 136.0 MB) ----
    char* ws = (char*)d_ws;
    float* invd  = (float*)(ws + 0);                 // 400,000
    int*   cnti  = (int*)(ws + 400000);              // 400,000
    int*   roff  = (int*)(ws + 800000);              // 400,004 (N+1)
    int*   woff  = (int*)(ws + 1200016);             // 400,000
    int*   bsum  = (int*)(ws + 1600016);             // 1,024
    int*   csr   = (int*)(ws + 1601056);             // 6,400,000
    __hip_bfloat16* h1 = (__hip_bfloat16*)(ws + 8001536);    // 51,200,000
    __hip_bfloat16* h2 = (__hip_bfloat16*)(ws + 59201536);   // 51,200,000
    __hip_bfloat16* M1 = h2;                                  // alias (h2 dead in L1)
    ushort_t* T1 = (ushort_t*)(ws + 110401536);               // 25,600,000 (xb / Y)
    const size_t WS_NEED = 136001536;
    if (ws_size < WS_NEED) return;  // clean diagnostic failure

    const int GB = (N + 63) / 64;  // 1563
    const int NB = (N + 1023) / 1024;  // 98

    // ---- CSR build ----
    hipMemsetAsync(cnti, 0, (size_t)N * 4, stream);
    count_int<<<(E + 255) / 256, 256, 0, stream>>>(dst, cnti, E);
    inv_from_cnt<<<(N + 255) / 256, 256, 0, stream>>>(cnti, invd, N);
    scan1<<<NB, 256, 0, stream>>>(cnti, roff, bsum, N);
    scan2<<<1, 256, 0, stream>>>(bsum, NB);
    scan3<<<(N + 256) / 256, 256, 0, stream>>>(roff, bsum, N, E);
    copy_int<<<(N + 255) / 256, 256, 0, stream>>>(roff, woff, N);
    reorder<<<(E + 255) / 256, 256, 0, stream>>>(src, dst, woff, csr, E);

    // ---- layer 1 (aggregate-first + fused concat GEMM) ----
    round_bf16<<<(N * 128 / 4 + 255) / 256, 256, 0, stream>>>(x, T1, (long)N * 128);
    gather_mean<__hip_bfloat16><<<(N * 64 + 255) / 256, 256, 0, stream>>>(
        T1, roff, csr, invd, M1, 128, 0);
    gemm64<128, true, false, __hip_bfloat16><<<dim3(GB, 4), 256, 0, stream>>>(
        M1, x, Wl1, Wr1, 256, 0, b1, h1, 256, 0);

    // ---- layer 2 (project-first, 2 chunks of 128, in-place epilogue) ----
    for (int c = 0; c < 256; c += 128) {
        gemm64<256, false, false, __hip_bfloat16><<<dim3(GB, 2), 256, 0, stream>>>(
            h1, nullptr, Wl2, nullptr, 256, c, nullptr, (__hip_bfloat16*)T1, 128, 0);
        gather_mean<__hip_bfloat16><<<(N * 64 + 255) / 256, 256, 0, stream>>>(
            T1, roff, csr, invd, h2, 256, c);
        gemm64<256, false, true, __hip_bfloat16><<<dim3(GB, 2), 256, 0, stream>>>(
            h1, nullptr, Wr2, nullptr, 256, c, b2, h2, 256, c);
    }

    // ---- layer 3 (project-first, single 128 chunk, f32 out) ----
    gemm64<256, false, false, __hip_bfloat16><<<dim3(GB, 2), 256, 0, stream>>>(
        h2, nullptr, Wl3, nullptr, 128, 0, nullptr, (__hip_bfloat16*)T1, 128, 0);
    gather_mean<float><<<(N * 64 + 255) / 256, 256, 0, stream>>>(
        T1, roff, csr, invd, (float*)d_out, 128, 0);
    gemm64<256, false, true, float><<<dim3(GB, 2), 256, 0, stream>>>(
        h2, nullptr, Wr3, nullptr, 128, 0, b3, (float*)d_out, 128, 0);
}

// Round 4
// 1067.857 us; speedup vs baseline: 4.0671x; 1.4502x over previous
//
#include <hip/hip_runtime.h>
#include <hip/hip_bf16.h>

#define N_NODES 100000

typedef unsigned short ushort_t;
typedef __attribute__((ext_vector_type(8))) short bf16x8;
typedef __attribute__((ext_vector_type(4))) float f32x4;

// ---------------- helpers ----------------
__device__ inline float bfbits2f(unsigned int lo16) { return __uint_as_float(lo16 << 16); }

__device__ inline ushort_t f2bfbits(float f) {
    __hip_bfloat16 h = __float2bfloat16(f);
    return *reinterpret_cast<ushort_t*>(&h);
}

// ---------------- degree count (int) ----------------
__global__ void count_int(const int* __restrict__ dst, int* __restrict__ cnt, int E) {
    int e = blockIdx.x * blockDim.x + threadIdx.x;
    if (e < E) {
        unsigned d = (unsigned)dst[e];
        if (d < N_NODES) atomicAdd(&cnt[d], 1);
    }
}

__global__ void inv_from_cnt(const int* __restrict__ cnt, float* __restrict__ invd, int n) {
    int i = blockIdx.x * blockDim.x + threadIdx.x;
    if (i < n) invd[i] = 1.0f / (float)max(cnt[i], 1);
}

// ---------------- exclusive scan (3 kernels) ----------------
__global__ __launch_bounds__(256) void scan1(const int* __restrict__ in, int* __restrict__ out,
                                             int* __restrict__ bsum, int n) {
    __shared__ int lds[256];
    const int t = threadIdx.x;
    const int base = blockIdx.x * 1024 + t * 4;
    int4 v = {0, 0, 0, 0};
    if (base + 3 < n) v = *(const int4*)(in + base);
    else {
        v.x = (base + 0 < n) ? in[base + 0] : 0;
        v.y = (base + 1 < n) ? in[base + 1] : 0;
        v.z = (base + 2 < n) ? in[base + 2] : 0;
        v.w = (base + 3 < n) ? in[base + 3] : 0;
    }
    int s0 = v.x, s1 = s0 + v.y, s2 = s1 + v.z, s3 = s2 + v.w;
    lds[t] = s3;
    __syncthreads();
    for (int off = 1; off < 256; off <<= 1) {
        int a = (t >= off) ? lds[t - off] : 0;
        __syncthreads();
        lds[t] += a;
        __syncthreads();
    }
    const int texcl = lds[t] - s3;
    if (t == 255) bsum[blockIdx.x] = lds[255];
    if (base + 0 < n) out[base + 0] = texcl;
    if (base + 1 < n) out[base + 1] = texcl + s0;
    if (base + 2 < n) out[base + 2] = texcl + s1;
    if (base + 3 < n) out[base + 3] = texcl + s2;
}

__global__ __launch_bounds__(256) void scan2(int* __restrict__ bsum, int nb) {
    __shared__ int lds[256];
    const int t = threadIdx.x;
    int v = (t < nb) ? bsum[t] : 0;
    lds[t] = v;
    __syncthreads();
    for (int off = 1; off < 256; off <<= 1) {
        int a = (t >= off) ? lds[t - off] : 0;
        __syncthreads();
        lds[t] += a;
        __syncthreads();
    }
    if (t < nb) bsum[t] = lds[t] - v;
}

__global__ void scan3(int* __restrict__ out, const int* __restrict__ bsum, int n, int E) {
    int i = blockIdx.x * blockDim.x + threadIdx.x;
    if (i < n) out[i] += bsum[i >> 10];
    if (i == 0) out[n] = E;
}

__global__ void copy_int(const int* __restrict__ a, int* __restrict__ b, int n) {
    int i = blockIdx.x * blockDim.x + threadIdx.x;
    if (i < n) b[i] = a[i];
}

// ---------------- reorder: bucket src by dst ----------------
__global__ void reorder(const int* __restrict__ src, const int* __restrict__ dst,
                        int* __restrict__ woff, int* __restrict__ csr, int E) {
    int e = blockIdx.x * blockDim.x + threadIdx.x;
    if (e < E) {
        unsigned d = (unsigned)dst[e], s = (unsigned)src[e];
        if (d < N_NODES && s < N_NODES) {
            int p = atomicAdd(&woff[d], 1);
            csr[p] = (int)s;
        }
    }
}

// ---------------- round f32 -> bf16 ----------------
__global__ void round_bf16(const float* __restrict__ x, ushort_t* __restrict__ xb, long n) {
    long i = ((long)blockIdx.x * blockDim.x + threadIdx.x) * 4;
    if (i < n) {
        float4 v = *(const float4*)(x + i);
        ushort4 o = {f2bfbits(v.x), f2bfbits(v.y), f2bfbits(v.z), f2bfbits(v.w)};
        *(ushort4*)(xb + i) = o;
    }
}

// ---------------- weight cvt + transpose: WT[j][kdst0+k] = bf16(W[k][j]) ----------------
__global__ void cvt_transpose(const float* __restrict__ W, ushort_t* __restrict__ WT,
                              int K, int J, int kdst0, int ldwt) {
    int idx = blockIdx.x * blockDim.x + threadIdx.x;
    if (idx >= K * J) return;
    int k = idx / J, j = idx - k * J;  // consecutive threads -> consecutive j (coalesced read)
    WT[(size_t)j * ldwt + kdst0 + k] = f2bfbits(W[idx]);
}

// ---------------- gather-mean: one wave per node, 128 bf16 cols ----------------
template <typename OT>
__global__ __launch_bounds__(256) void gather_mean(const ushort_t* __restrict__ Y,
                                                   const int* __restrict__ roff,
                                                   const int* __restrict__ csr,
                                                   const float* __restrict__ invd,
                                                   OT* __restrict__ out, int out_ld, int col0) {
    const int w = (blockIdx.x * blockDim.x + threadIdx.x) >> 6;  // node
    const int lane = threadIdx.x & 63;
    if (w >= N_NODES) return;
    const int e0 = roff[w], e1 = roff[w + 1];
    const unsigned int* yp = (const unsigned int*)Y;  // row = 64 uints (128 bf16)
    float a0 = 0.0f, a1 = 0.0f;
    int s = (e0 < e1) ? csr[e0] : 0;
    for (int e = e0; e < e1; ++e) {
        int sn = (e + 1 < e1) ? csr[e + 1] : 0;
        unsigned int u = yp[(size_t)s * 64 + lane];
        a0 += bfbits2f(u & 0xffffu);
        a1 += __uint_as_float(u & 0xffff0000u);
        s = sn;
    }
    const float iv = invd[w];
    a0 *= iv; a1 *= iv;
    if constexpr (sizeof(OT) == 4) {
        float2 st = {a0, a1};
        *(float2*)((float*)out + (size_t)w * out_ld + col0 + lane * 2) = st;
    } else {
        ushort2 st = {f2bfbits(a0), f2bfbits(a1)};
        *(ushort2*)((ushort_t*)out + (size_t)w * out_ld + col0 + lane * 2) = st;
    }
}

// ---------------- MFMA GEMM: 128x128 tile, BK=64, 4 waves, 16x16x32 bf16 ----------------
// out[row][ocolbase+lcol] (+= existing if EPI) = (BR? relu(acc + bias[wcolbase+lcol]) : acc)
// A: [N x KH] bf16. CONCAT: k<KH from A, k>=KH from A2 (both stride KH).
// WT: [J x KTOT] bf16 (transposed weights); B-tile rows = out cols.
template <int KH, bool CONCAT, bool EPI, bool BR, typename OT>
__global__ __launch_bounds__(256) void mfma_gemm(const ushort_t* __restrict__ A,
                                                 const ushort_t* __restrict__ A2,
                                                 const ushort_t* __restrict__ WT,
                                                 const float* __restrict__ bias,
                                                 OT* __restrict__ out, int out_ld,
                                                 int jrow0, int oc0) {
    constexpr int KTOT = CONCAT ? 2 * KH : KH;
    constexpr int BK = 64;
    __shared__ ushort_t smem[16384];  // A: [128][64] swz (16KB) + B: [128][64] swz (16KB)
    ushort_t* As = smem;
    ushort_t* Bs = smem + 8192;

    const int tid = threadIdx.x;
    const int lane = tid & 63;
    const int w = tid >> 6;
    const int wr = w >> 1, wc = w & 1;
    const int n0 = blockIdx.x * 128;
    const int wcolbase = jrow0 + blockIdx.y * 128;  // W col / WT row / bias base
    const int ocolbase = oc0 + blockIdx.y * 128;    // out col base

    // staging: chunk ci = 8 rows x 64 k (1024 B); lane covers (row = ci*8 + srow, 16B at skc)
    const int srow = lane >> 3;               // 0..7
    const int skc = (lane & 7) ^ srow;        // pre-swizzled source k-chunk (rule #21)

    f32x4 acc[4][4];
#pragma unroll
    for (int m = 0; m < 4; ++m)
#pragma unroll
        for (int n = 0; n < 4; ++n) acc[m][n] = (f32x4){0.f, 0.f, 0.f, 0.f};

    for (int k0 = 0; k0 < KTOT; k0 += BK) {
        const ushort_t* Asrc = A;
        int ak = k0;
        if (CONCAT && k0 >= KH) { Asrc = A2; ak = k0 - KH; }
#pragma unroll
        for (int i = 0; i < 4; ++i) {
            const int ci = w * 4 + i;
            int grow = n0 + ci * 8 + srow;
            grow = min(grow, N_NODES - 1);  // clamp: dup rows, never stored
            const ushort_t* g = Asrc + (size_t)grow * KH + ak + skc * 8;
            __builtin_amdgcn_global_load_lds((const unsigned int*)g,
                                             (unsigned int*)(As + ci * 512), 16, 0, 0);
        }
#pragma unroll
        for (int i = 0; i < 4; ++i) {
            const int ci = w * 4 + i;
            const int jrow = wcolbase + ci * 8 + srow;
            const ushort_t* g = WT + (size_t)jrow * KTOT + k0 + skc * 8;
            __builtin_amdgcn_global_load_lds((const unsigned int*)g,
                                             (unsigned int*)(Bs + ci * 512), 16, 0, 0);
        }
        __syncthreads();

#pragma unroll
        for (int kk = 0; kk < 2; ++kk) {
            const int kc = kk * 4 + (lane >> 4);
            bf16x8 af[4], bf[4];
#pragma unroll
            for (int m = 0; m < 4; ++m) {
                const int row = wr * 64 + m * 16 + (lane & 15);
                af[m] = *(const bf16x8*)((const char*)As + row * 128 + ((kc ^ (row & 7)) << 4));
            }
#pragma unroll
            for (int n = 0; n < 4; ++n) {
                const int row = wc * 64 + n * 16 + (lane & 15);
                bf[n] = *(const bf16x8*)((const char*)Bs + row * 128 + ((kc ^ (row & 7)) << 4));
            }
#pragma unroll
            for (int m = 0; m < 4; ++m)
#pragma unroll
                for (int n = 0; n < 4; ++n)
                    acc[m][n] = __builtin_amdgcn_mfma_f32_16x16x32_bf16(af[m], bf[n],
                                                                        acc[m][n], 0, 0, 0);
        }
        __syncthreads();
    }

    // epilogue: C/D layout col=lane&15, row=(lane>>4)*4+q (m89-verified)
    const int c15 = lane & 15;
    const int r4 = (lane >> 4) * 4;
#pragma unroll
    for (int m = 0; m < 4; ++m) {
#pragma unroll
        for (int q = 0; q < 4; ++q) {
            const int row_g = n0 + wr * 64 + m * 16 + r4 + q;
            if (row_g >= N_NODES) continue;
#pragma unroll
            for (int n = 0; n < 4; ++n) {
                const int lcol = wc * 64 + n * 16 + c15;
                float v = acc[m][n][q];
                OT* op = out + (size_t)row_g * out_ld + ocolbase + lcol;
                if constexpr (EPI) {
                    if constexpr (sizeof(OT) == 4) v += *(const float*)op;
                    else v += bfbits2f(*(const ushort_t*)op);
                }
                if constexpr (BR) v = fmaxf(v + bias[wcolbase + lcol], 0.0f);
                if constexpr (sizeof(OT) == 4) *(float*)op = v;
                else *(ushort_t*)op = f2bfbits(v);
            }
        }
    }
}

// ---------------- launch ----------------
extern "C" void kernel_launch(void* const* d_in, const int* in_sizes, int n_in,
                              void* d_out, int out_size, void* d_ws, size_t ws_size,
                              hipStream_t stream) {
    const float* x   = (const float*)d_in[0];
    const int*   ei  = (const int*)d_in[1];
    const float* Wl1 = (const float*)d_in[2];
    const float* Wr1 = (const float*)d_in[3];
    const float* b1  = (const float*)d_in[4];
    const float* Wl2 = (const float*)d_in[5];
    const float* Wr2 = (const float*)d_in[6];
    const float* b2  = (const float*)d_in[7];
    const float* Wl3 = (const float*)d_in[8];
    const float* Wr3 = (const float*)d_in[9];
    const float* b3  = (const float*)d_in[10];

    const int E = in_sizes[1] / 2;
    const int* src = ei;
    const int* dst = ei + E;
    const int N = N_NODES;

    // ---- workspace arena (136.5 MB; round-2 proved >=153.6 MB available) ----
    char* ws = (char*)d_ws;
    float* invd = (float*)(ws + 0);            // 400,000
    int* cnti   = (int*)(ws + 400000);         // 400,000
    int* roff   = (int*)(ws + 800000);         // 400,004 (N+1)
    int* woff   = (int*)(ws + 1200016);        // 400,000
    int* bsum   = (int*)(ws + 1600016);        // 1,024
    ushort_t* WT1  = (ushort_t*)(ws + 1601040);  // 256x256 bf16 = 131,072
    ushort_t* WT2l = (ushort_t*)(ws + 1732112);  // 131,072
    ushort_t* WT2r = (ushort_t*)(ws + 1863184);  // 131,072
    ushort_t* WT3l = (ushort_t*)(ws + 1994256);  // 128x256 = 65,536
    ushort_t* WT3r = (ushort_t*)(ws + 2059792);  // 65,536
    int* csr = (int*)(ws + 2125328);             // 6,400,000
    ushort_t* h1 = (ushort_t*)(ws + 8525328);    // N x 256 bf16 = 51,200,000
    ushort_t* h2 = (ushort_t*)(ws + 59725328);   // 51,200,000
    ushort_t* M1 = h2;                            // alias (h2 dead during L1)
    ushort_t* T1 = (ushort_t*)(ws + 110925328);  // N x 128 bf16 = 25,600,000
    const size_t WS_NEED = 136525328;
    if (ws_size < WS_NEED) return;

    const int NB = (N + 1023) / 1024;  // 98
    const int GX = (N + 127) / 128;    // 782

    // ---- CSR build ----
    hipMemsetAsync(cnti, 0, (size_t)N * 4, stream);
    count_int<<<(E + 255) / 256, 256, 0, stream>>>(dst, cnti, E);
    inv_from_cnt<<<(N + 255) / 256, 256, 0, stream>>>(cnti, invd, N);
    scan1<<<NB, 256, 0, stream>>>(cnti, roff, bsum, N);
    scan2<<<1, 256, 0, stream>>>(bsum, NB);
    scan3<<<(N + 256) / 256, 256, 0, stream>>>(roff, bsum, N, E);
    copy_int<<<(N + 255) / 256, 256, 0, stream>>>(roff, woff, N);
    reorder<<<(E + 255) / 256, 256, 0, stream>>>(src, dst, woff, csr, E);

    // ---- weight prep: bf16 transposed copies ----
    cvt_transpose<<<(128 * 256 + 255) / 256, 256, 0, stream>>>(Wl1, WT1, 128, 256, 0, 256);
    cvt_transpose<<<(128 * 256 + 255) / 256, 256, 0, stream>>>(Wr1, WT1, 128, 256, 128, 256);
    cvt_transpose<<<(256 * 256 + 255) / 256, 256, 0, stream>>>(Wl2, WT2l, 256, 256, 0, 256);
    cvt_transpose<<<(256 * 256 + 255) / 256, 256, 0, stream>>>(Wr2, WT2r, 256, 256, 0, 256);
    cvt_transpose<<<(256 * 128 + 255) / 256, 256, 0, stream>>>(Wl3, WT3l, 256, 128, 0, 256);
    cvt_transpose<<<(256 * 128 + 255) / 256, 256, 0, stream>>>(Wr3, WT3r, 256, 128, 0, 256);

    // ---- layer 1: aggregate-first + fused concat GEMM ----
    round_bf16<<<(N * 128 / 4 + 255) / 256, 256, 0, stream>>>(x, T1, (long)N * 128);
    gather_mean<ushort_t><<<(N * 64 + 255) / 256, 256, 0, stream>>>(
        T1, roff, csr, invd, M1, 128, 0);
    // h1 = relu([M1 | x_bf16] @ [Wl1;Wr1] + b1)
    mfma_gemm<128, true, false, true, ushort_t><<<dim3(GX, 2), 256, 0, stream>>>(
        M1, T1, WT1, b1, h1, 256, 0, 0);

    // ---- layer 2: project-first per 128-col chunk ----
    for (int c = 0; c < 256; c += 128) {
        mfma_gemm<256, false, false, false, ushort_t><<<dim3(GX, 1), 256, 0, stream>>>(
            h1, nullptr, WT2l, nullptr, T1, 128, c, 0);
        gather_mean<ushort_t><<<(N * 64 + 255) / 256, 256, 0, stream>>>(
            T1, roff, csr, invd, h2, 256, c);
        mfma_gemm<256, false, true, true, ushort_t><<<dim3(GX, 1), 256, 0, stream>>>(
            h1, nullptr, WT2r, b2, h2, 256, c, c);
    }

    // ---- layer 3: project-first, f32 out ----
    mfma_gemm<256, false, false, false, ushort_t><<<dim3(GX, 1), 256, 0, stream>>>(
        h2, nullptr, WT3l, nullptr, T1, 128, 0, 0);
    gather_mean<float><<<(N * 64 + 255) / 256, 256, 0, stream>>>(
        T1, roff, csr, invd, (float*)d_out, 128, 0);
    mfma_gemm<256, false, true, true, float><<<dim3(GX, 1), 256, 0, stream>>>(
        h2, nullptr, WT3r, b3, (float*)d_out, 128, 0, 0);
}

// Round 5
// 745.489 us; speedup vs baseline: 5.8258x; 1.4324x over previous
//
#include <hip/hip_runtime.h>
#include <hip/hip_bf16.h>

#define N_NODES 100000

typedef unsigned short ushort_t;
typedef __attribute__((ext_vector_type(8))) short bf16x8;
typedef __attribute__((ext_vector_type(4))) float f32x4;

// ---------------- helpers ----------------
__device__ inline float bfbits2f(unsigned int lo16) { return __uint_as_float(lo16 << 16); }

__device__ inline ushort_t f2bfbits(float f) {
    __hip_bfloat16 h = __float2bfloat16(f);
    return *reinterpret_cast<ushort_t*>(&h);
}

// ---------------- degree count (int) ----------------
__global__ void count_int(const int* __restrict__ dst, int* __restrict__ cnt, int E) {
    int e = blockIdx.x * blockDim.x + threadIdx.x;
    if (e < E) {
        unsigned d = (unsigned)dst[e];
        if (d < N_NODES) atomicAdd(&cnt[d], 1);
    }
}

__global__ void inv_from_cnt(const int* __restrict__ cnt, float* __restrict__ invd, int n) {
    int i = blockIdx.x * blockDim.x + threadIdx.x;
    if (i < n) invd[i] = 1.0f / (float)max(cnt[i], 1);
}

// ---------------- exclusive scan (3 kernels) ----------------
__global__ __launch_bounds__(256) void scan1(const int* __restrict__ in, int* __restrict__ out,
                                             int* __restrict__ bsum, int n) {
    __shared__ int lds[256];
    const int t = threadIdx.x;
    const int base = blockIdx.x * 1024 + t * 4;
    int4 v = {0, 0, 0, 0};
    if (base + 3 < n) v = *(const int4*)(in + base);
    else {
        v.x = (base + 0 < n) ? in[base + 0] : 0;
        v.y = (base + 1 < n) ? in[base + 1] : 0;
        v.z = (base + 2 < n) ? in[base + 2] : 0;
        v.w = (base + 3 < n) ? in[base + 3] : 0;
    }
    int s0 = v.x, s1 = s0 + v.y, s2 = s1 + v.z, s3 = s2 + v.w;
    lds[t] = s3;
    __syncthreads();
    for (int off = 1; off < 256; off <<= 1) {
        int a = (t >= off) ? lds[t - off] : 0;
        __syncthreads();
        lds[t] += a;
        __syncthreads();
    }
    const int texcl = lds[t] - s3;
    if (t == 255) bsum[blockIdx.x] = lds[255];
    if (base + 0 < n) out[base + 0] = texcl;
    if (base + 1 < n) out[base + 1] = texcl + s0;
    if (base + 2 < n) out[base + 2] = texcl + s1;
    if (base + 3 < n) out[base + 3] = texcl + s2;
}

__global__ __launch_bounds__(256) void scan2(int* __restrict__ bsum, int nb) {
    __shared__ int lds[256];
    const int t = threadIdx.x;
    int v = (t < nb) ? bsum[t] : 0;
    lds[t] = v;
    __syncthreads();
    for (int off = 1; off < 256; off <<= 1) {
        int a = (t >= off) ? lds[t - off] : 0;
        __syncthreads();
        lds[t] += a;
        __syncthreads();
    }
    if (t < nb) bsum[t] = lds[t] - v;
}

__global__ void scan3(int* __restrict__ out, const int* __restrict__ bsum, int n, int E) {
    int i = blockIdx.x * blockDim.x + threadIdx.x;
    if (i < n) out[i] += bsum[i >> 10];
    if (i == 0) out[n] = E;
}

__global__ void copy_int(const int* __restrict__ a, int* __restrict__ b, int n) {
    int i = blockIdx.x * blockDim.x + threadIdx.x;
    if (i < n) b[i] = a[i];
}

// ---------------- reorder: bucket src by dst ----------------
__global__ void reorder(const int* __restrict__ src, const int* __restrict__ dst,
                        int* __restrict__ woff, int* __restrict__ csr, int E) {
    int e = blockIdx.x * blockDim.x + threadIdx.x;
    if (e < E) {
        unsigned d = (unsigned)dst[e], s = (unsigned)src[e];
        if (d < N_NODES && s < N_NODES) {
            int p = atomicAdd(&woff[d], 1);
            csr[p] = (int)s;
        }
    }
}

// ---------------- round f32 -> bf16 ----------------
__global__ void round_bf16(const float* __restrict__ x, ushort_t* __restrict__ xb, long n) {
    long i = ((long)blockIdx.x * blockDim.x + threadIdx.x) * 4;
    if (i < n) {
        float4 v = *(const float4*)(x + i);
        ushort4 o = {f2bfbits(v.x), f2bfbits(v.y), f2bfbits(v.z), f2bfbits(v.w)};
        *(ushort4*)(xb + i) = o;
    }
}

// ---------------- weight cvt + transpose: WT[j][kdst0+k] = bf16(W[k][j]) ----------------
__global__ void cvt_transpose(const float* __restrict__ W, ushort_t* __restrict__ WT,
                              int K, int J, int kdst0, int ldwt) {
    int idx = blockIdx.x * blockDim.x + threadIdx.x;
    if (idx >= K * J) return;
    int k = idx / J, j = idx - k * J;
    WT[(size_t)j * ldwt + kdst0 + k] = f2bfbits(W[idx]);
}

// ---------------- gather-mean v2: one wave per node, 4 edge-groups x 16 lanes ----------------
// Each 16-lane group processes one edge at a time (lane loads uint4 = 16B of the
// 256B row); 2x manual unroll -> ~8 independent row loads in flight per wave.
// Cross-group reduce via __shfl_xor(16/32); group 0 stores the row.
template <typename OT>
__global__ __launch_bounds__(256) void gather_mean(const ushort_t* __restrict__ Y,
                                                   const int* __restrict__ roff,
                                                   const int* __restrict__ csr,
                                                   const float* __restrict__ invd,
                                                   OT* __restrict__ out, int out_ld, int col0) {
    const int w = (blockIdx.x * blockDim.x + threadIdx.x) >> 6;  // node
    if (w >= N_NODES) return;
    const int lane = threadIdx.x & 63;
    const int g = lane >> 4;        // edge group 0..3
    const int l = lane & 15;        // 16B chunk within row
    const int e0 = roff[w], e1 = roff[w + 1];

    float a[8] = {0.f, 0.f, 0.f, 0.f, 0.f, 0.f, 0.f, 0.f};

    int e = e0 + g;
    for (; e + 4 < e1; e += 8) {
        const int s0 = csr[e];
        const int s1 = csr[e + 4];
        uint4 u0 = *(const uint4*)(Y + (size_t)s0 * 128 + l * 8);
        uint4 u1 = *(const uint4*)(Y + (size_t)s1 * 128 + l * 8);
        a[0] += bfbits2f(u0.x & 0xffffu); a[1] += __uint_as_float(u0.x & 0xffff0000u);
        a[2] += bfbits2f(u0.y & 0xffffu); a[3] += __uint_as_float(u0.y & 0xffff0000u);
        a[4] += bfbits2f(u0.z & 0xffffu); a[5] += __uint_as_float(u0.z & 0xffff0000u);
        a[6] += bfbits2f(u0.w & 0xffffu); a[7] += __uint_as_float(u0.w & 0xffff0000u);
        a[0] += bfbits2f(u1.x & 0xffffu); a[1] += __uint_as_float(u1.x & 0xffff0000u);
        a[2] += bfbits2f(u1.y & 0xffffu); a[3] += __uint_as_float(u1.y & 0xffff0000u);
        a[4] += bfbits2f(u1.z & 0xffffu); a[5] += __uint_as_float(u1.z & 0xffff0000u);
        a[6] += bfbits2f(u1.w & 0xffffu); a[7] += __uint_as_float(u1.w & 0xffff0000u);
    }
    if (e < e1) {
        const int s0 = csr[e];
        uint4 u0 = *(const uint4*)(Y + (size_t)s0 * 128 + l * 8);
        a[0] += bfbits2f(u0.x & 0xffffu); a[1] += __uint_as_float(u0.x & 0xffff0000u);
        a[2] += bfbits2f(u0.y & 0xffffu); a[3] += __uint_as_float(u0.y & 0xffff0000u);
        a[4] += bfbits2f(u0.z & 0xffffu); a[5] += __uint_as_float(u0.z & 0xffff0000u);
        a[6] += bfbits2f(u0.w & 0xffffu); a[7] += __uint_as_float(u0.w & 0xffff0000u);
    }

    // reduce across the 4 groups
#pragma unroll
    for (int i = 0; i < 8; ++i) {
        a[i] += __shfl_xor(a[i], 16);
        a[i] += __shfl_xor(a[i], 32);
    }

    if (g != 0) return;
    const float iv = invd[w];
#pragma unroll
    for (int i = 0; i < 8; ++i) a[i] *= iv;

    if constexpr (sizeof(OT) == 4) {  // f32 out: 8 floats = 2 float4
        float* op = (float*)out + (size_t)w * out_ld + col0 + l * 8;
        float4 s0 = {a[0], a[1], a[2], a[3]};
        float4 s1 = {a[4], a[5], a[6], a[7]};
        *(float4*)op = s0;
        *(float4*)(op + 4) = s1;
    } else {  // bf16 out: 8 bf16 = 16B
        ushort_t* op = (ushort_t*)out + (size_t)w * out_ld + col0 + l * 8;
        ushort4 lohi0 = {f2bfbits(a[0]), f2bfbits(a[1]), f2bfbits(a[2]), f2bfbits(a[3])};
        ushort4 lohi1 = {f2bfbits(a[4]), f2bfbits(a[5]), f2bfbits(a[6]), f2bfbits(a[7])};
        *(ushort4*)op = lohi0;
        *(ushort4*)(op + 4) = lohi1;
    }
}

// ---------------- MFMA GEMM: 128x128 tile, BK=64, 4 waves, 16x16x32 bf16 ----------------
template <int KH, bool CONCAT, bool EPI, bool BR, typename OT>
__global__ __launch_bounds__(256) void mfma_gemm(const ushort_t* __restrict__ A,
                                                 const ushort_t* __restrict__ A2,
                                                 const ushort_t* __restrict__ WT,
                                                 const float* __restrict__ bias,
                                                 OT* __restrict__ out, int out_ld,
                                                 int jrow0, int oc0) {
    constexpr int KTOT = CONCAT ? 2 * KH : KH;
    constexpr int BK = 64;
    __shared__ ushort_t smem[16384];
    ushort_t* As = smem;
    ushort_t* Bs = smem + 8192;

    const int tid = threadIdx.x;
    const int lane = tid & 63;
    const int w = tid >> 6;
    const int wr = w >> 1, wc = w & 1;
    const int n0 = blockIdx.x * 128;
    const int wcolbase = jrow0 + blockIdx.y * 128;
    const int ocolbase = oc0 + blockIdx.y * 128;

    const int srow = lane >> 3;
    const int skc = (lane & 7) ^ srow;

    f32x4 acc[4][4];
#pragma unroll
    for (int m = 0; m < 4; ++m)
#pragma unroll
        for (int n = 0; n < 4; ++n) acc[m][n] = (f32x4){0.f, 0.f, 0.f, 0.f};

    for (int k0 = 0; k0 < KTOT; k0 += BK) {
        const ushort_t* Asrc = A;
        int ak = k0;
        if (CONCAT && k0 >= KH) { Asrc = A2; ak = k0 - KH; }
#pragma unroll
        for (int i = 0; i < 4; ++i) {
            const int ci = w * 4 + i;
            int grow = n0 + ci * 8 + srow;
            grow = min(grow, N_NODES - 1);
            const ushort_t* g = Asrc + (size_t)grow * KH + ak + skc * 8;
            __builtin_amdgcn_global_load_lds((const unsigned int*)g,
                                             (unsigned int*)(As + ci * 512), 16, 0, 0);
        }
#pragma unroll
        for (int i = 0; i < 4; ++i) {
            const int ci = w * 4 + i;
            const int jrow = wcolbase + ci * 8 + srow;
            const ushort_t* g = WT + (size_t)jrow * KTOT + k0 + skc * 8;
            __builtin_amdgcn_global_load_lds((const unsigned int*)g,
                                             (unsigned int*)(Bs + ci * 512), 16, 0, 0);
        }
        __syncthreads();

#pragma unroll
        for (int kk = 0; kk < 2; ++kk) {
            const int kc = kk * 4 + (lane >> 4);
            bf16x8 af[4], bf[4];
#pragma unroll
            for (int m = 0; m < 4; ++m) {
                const int row = wr * 64 + m * 16 + (lane & 15);
                af[m] = *(const bf16x8*)((const char*)As + row * 128 + ((kc ^ (row & 7)) << 4));
            }
#pragma unroll
            for (int n = 0; n < 4; ++n) {
                const int row = wc * 64 + n * 16 + (lane & 15);
                bf[n] = *(const bf16x8*)((const char*)Bs + row * 128 + ((kc ^ (row & 7)) << 4));
            }
#pragma unroll
            for (int m = 0; m < 4; ++m)
#pragma unroll
                for (int n = 0; n < 4; ++n)
                    acc[m][n] = __builtin_amdgcn_mfma_f32_16x16x32_bf16(af[m], bf[n],
                                                                        acc[m][n], 0, 0, 0);
        }
        __syncthreads();
    }

    const int c15 = lane & 15;
    const int r4 = (lane >> 4) * 4;
#pragma unroll
    for (int m = 0; m < 4; ++m) {
#pragma unroll
        for (int q = 0; q < 4; ++q) {
            const int row_g = n0 + wr * 64 + m * 16 + r4 + q;
            if (row_g >= N_NODES) continue;
#pragma unroll
            for (int n = 0; n < 4; ++n) {
                const int lcol = wc * 64 + n * 16 + c15;
                float v = acc[m][n][q];
                OT* op = out + (size_t)row_g * out_ld + ocolbase + lcol;
                if constexpr (EPI) {
                    if constexpr (sizeof(OT) == 4) v += *(const float*)op;
                    else v += bfbits2f(*(const ushort_t*)op);
                }
                if constexpr (BR) v = fmaxf(v + bias[wcolbase + lcol], 0.0f);
                if constexpr (sizeof(OT) == 4) *(float*)op = v;
                else *(ushort_t*)op = f2bfbits(v);
            }
        }
    }
}

// ---------------- launch ----------------
extern "C" void kernel_launch(void* const* d_in, const int* in_sizes, int n_in,
                              void* d_out, int out_size, void* d_ws, size_t ws_size,
                              hipStream_t stream) {
    const float* x   = (const float*)d_in[0];
    const int*   ei  = (const int*)d_in[1];
    const float* Wl1 = (const float*)d_in[2];
    const float* Wr1 = (const float*)d_in[3];
    const float* b1  = (const float*)d_in[4];
    const float* Wl2 = (const float*)d_in[5];
    const float* Wr2 = (const float*)d_in[6];
    const float* b2  = (const float*)d_in[7];
    const float* Wl3 = (const float*)d_in[8];
    const float* Wr3 = (const float*)d_in[9];
    const float* b3  = (const float*)d_in[10];

    const int E = in_sizes[1] / 2;
    const int* src = ei;
    const int* dst = ei + E;
    const int N = N_NODES;

    // ---- workspace arena (136.5 MB) ----
    char* ws = (char*)d_ws;
    float* invd = (float*)(ws + 0);
    int* cnti   = (int*)(ws + 400000);
    int* roff   = (int*)(ws + 800000);
    int* woff   = (int*)(ws + 1200016);
    int* bsum   = (int*)(ws + 1600016);
    ushort_t* WT1  = (ushort_t*)(ws + 1601040);
    ushort_t* WT2l = (ushort_t*)(ws + 1732112);
    ushort_t* WT2r = (ushort_t*)(ws + 1863184);
    ushort_t* WT3l = (ushort_t*)(ws + 1994256);
    ushort_t* WT3r = (ushort_t*)(ws + 2059792);
    int* csr = (int*)(ws + 2125328);
    ushort_t* h1 = (ushort_t*)(ws + 8525328);
    ushort_t* h2 = (ushort_t*)(ws + 59725328);
    ushort_t* M1 = h2;
    ushort_t* T1 = (ushort_t*)(ws + 110925328);
    const size_t WS_NEED = 136525328;
    if (ws_size < WS_NEED) return;

    const int NB = (N + 1023) / 1024;
    const int GX = (N + 127) / 128;

    // ---- CSR build ----
    hipMemsetAsync(cnti, 0, (size_t)N * 4, stream);
    count_int<<<(E + 255) / 256, 256, 0, stream>>>(dst, cnti, E);
    inv_from_cnt<<<(N + 255) / 256, 256, 0, stream>>>(cnti, invd, N);
    scan1<<<NB, 256, 0, stream>>>(cnti, roff, bsum, N);
    scan2<<<1, 256, 0, stream>>>(bsum, NB);
    scan3<<<(N + 256) / 256, 256, 0, stream>>>(roff, bsum, N, E);
    copy_int<<<(N + 255) / 256, 256, 0, stream>>>(roff, woff, N);
    reorder<<<(E + 255) / 256, 256, 0, stream>>>(src, dst, woff, csr, E);

    // ---- weight prep ----
    cvt_transpose<<<(128 * 256 + 255) / 256, 256, 0, stream>>>(Wl1, WT1, 128, 256, 0, 256);
    cvt_transpose<<<(128 * 256 + 255) / 256, 256, 0, stream>>>(Wr1, WT1, 128, 256, 128, 256);
    cvt_transpose<<<(256 * 256 + 255) / 256, 256, 0, stream>>>(Wl2, WT2l, 256, 256, 0, 256);
    cvt_transpose<<<(256 * 256 + 255) / 256, 256, 0, stream>>>(Wr2, WT2r, 256, 256, 0, 256);
    cvt_transpose<<<(256 * 128 + 255) / 256, 256, 0, stream>>>(Wl3, WT3l, 256, 128, 0, 256);
    cvt_transpose<<<(256 * 128 + 255) / 256, 256, 0, stream>>>(Wr3, WT3r, 256, 128, 0, 256);

    // ---- layer 1 ----
    round_bf16<<<(N * 128 / 4 + 255) / 256, 256, 0, stream>>>(x, T1, (long)N * 128);
    gather_mean<ushort_t><<<(N * 64 + 255) / 256, 256, 0, stream>>>(
        T1, roff, csr, invd, M1, 128, 0);
    mfma_gemm<128, true, false, true, ushort_t><<<dim3(GX, 2), 256, 0, stream>>>(
        M1, T1, WT1, b1, h1, 256, 0, 0);

    // ---- layer 2 ----
    for (int c = 0; c < 256; c += 128) {
        mfma_gemm<256, false, false, false, ushort_t><<<dim3(GX, 1), 256, 0, stream>>>(
            h1, nullptr, WT2l, nullptr, T1, 128, c, 0);
        gather_mean<ushort_t><<<(N * 64 + 255) / 256, 256, 0, stream>>>(
            T1, roff, csr, invd, h2, 256, c);
        mfma_gemm<256, false, true, true, ushort_t><<<dim3(GX, 1), 256, 0, stream>>>(
            h1, nullptr, WT2r, b2, h2, 256, c, c);
    }

    // ---- layer 3 ----
    mfma_gemm<256, false, false, false, ushort_t><<<dim3(GX, 1), 256, 0, stream>>>(
        h2, nullptr, WT3l, nullptr, T1, 128, 0, 0);
    gather_mean<float><<<(N * 64 + 255) / 256, 256, 0, stream>>>(
        T1, roff, csr, invd, (float*)d_out, 128, 0);
    mfma_gemm<256, false, true, true, float><<<dim3(GX, 1), 256, 0, stream>>>(
        h2, nullptr, WT3r, b3, (float*)d_out, 128, 0, 0);
}

// Round 6
// 659.841 us; speedup vs baseline: 6.5820x; 1.1298x over previous
//
#include <hip/hip_runtime.h>
#include <hip/hip_bf16.h>

#define N_NODES 100000
#define NBUK 391        // ceil(N_NODES / 256)
#define CHUNK 16384     // edges per hist1/binA block

typedef unsigned short ushort_t;
typedef __attribute__((ext_vector_type(8))) short bf16x8;
typedef __attribute__((ext_vector_type(4))) float f32x4;

// ---------------- helpers ----------------
__device__ inline float bfbits2f(unsigned int lo16) { return __uint_as_float(lo16 << 16); }

__device__ inline ushort_t f2bfbits(float f) {
    __hip_bfloat16 h = __float2bfloat16(f);
    return *reinterpret_cast<ushort_t*>(&h);
}

__device__ inline void acc8(float* a, uint4 u) {
    a[0] += bfbits2f(u.x & 0xffffu); a[1] += __uint_as_float(u.x & 0xffff0000u);
    a[2] += bfbits2f(u.y & 0xffffu); a[3] += __uint_as_float(u.y & 0xffff0000u);
    a[4] += bfbits2f(u.z & 0xffffu); a[5] += __uint_as_float(u.z & 0xffff0000u);
    a[6] += bfbits2f(u.w & 0xffffu); a[7] += __uint_as_float(u.w & 0xffff0000u);
}

// ---------------- exclusive scan (3 kernels) ----------------
__global__ __launch_bounds__(256) void scan1(const int* __restrict__ in, int* __restrict__ out,
                                             int* __restrict__ bsum, int n) {
    __shared__ int lds[256];
    const int t = threadIdx.x;
    const int base = blockIdx.x * 1024 + t * 4;
    int4 v = {0, 0, 0, 0};
    if (base + 3 < n) v = *(const int4*)(in + base);
    else {
        v.x = (base + 0 < n) ? in[base + 0] : 0;
        v.y = (base + 1 < n) ? in[base + 1] : 0;
        v.z = (base + 2 < n) ? in[base + 2] : 0;
        v.w = (base + 3 < n) ? in[base + 3] : 0;
    }
    int s0 = v.x, s1 = s0 + v.y, s2 = s1 + v.z, s3 = s2 + v.w;
    lds[t] = s3;
    __syncthreads();
    for (int off = 1; off < 256; off <<= 1) {
        int a = (t >= off) ? lds[t - off] : 0;
        __syncthreads();
        lds[t] += a;
        __syncthreads();
    }
    const int texcl = lds[t] - s3;
    if (t == 255) bsum[blockIdx.x] = lds[255];
    if (base + 0 < n) out[base + 0] = texcl;
    if (base + 1 < n) out[base + 1] = texcl + s0;
    if (base + 2 < n) out[base + 2] = texcl + s1;
    if (base + 3 < n) out[base + 3] = texcl + s2;
}

__global__ __launch_bounds__(256) void scan2(int* __restrict__ bsum, int nb) {
    __shared__ int lds[256];
    const int t = threadIdx.x;
    int v = (t < nb) ? bsum[t] : 0;
    lds[t] = v;
    __syncthreads();
    for (int off = 1; off < 256; off <<= 1) {
        int a = (t >= off) ? lds[t - off] : 0;
        __syncthreads();
        lds[t] += a;
        __syncthreads();
    }
    if (t < nb) bsum[t] = lds[t] - v;
}

__global__ void scan3(int* __restrict__ out, const int* __restrict__ bsum, int n, int E) {
    int i = blockIdx.x * blockDim.x + threadIdx.x;
    if (i < n) out[i] += bsum[i >> 10];
    if (i == 0) out[n] = E;
}

// ---------------- bucket sort: coarse histogram per chunk ----------------
__global__ __launch_bounds__(256) void hist1(const int* __restrict__ dst, int* __restrict__ H,
                                             int E, int NC) {
    __shared__ int h[NBUK + 1];
    const int t = threadIdx.x, c = blockIdx.x;
    for (int g = t; g <= NBUK; g += 256) h[g] = 0;
    __syncthreads();
    const long base = (long)c * CHUNK;
#pragma unroll 4
    for (int it = 0; it < CHUNK / 256; ++it) {
        long e = base + it * 256 + t;
        if (e < E) atomicAdd(&h[((unsigned)dst[e]) >> 8], 1);
    }
    __syncthreads();
    for (int g = t; g < NBUK; g += 256) H[(size_t)g * NC + c] = h[g];
}

// ---------------- bucket sort: bin (dst,src) pairs into coarse buckets ----------------
__global__ __launch_bounds__(256) void binA(const int* __restrict__ src,
                                            const int* __restrict__ dst,
                                            const int* __restrict__ Hs,  // scanned
                                            uint2* __restrict__ tmp, int E, int NC) {
    __shared__ int base_[NBUK + 1];
    __shared__ int r[NBUK + 1];
    const int t = threadIdx.x, c = blockIdx.x;
    for (int g = t; g <= NBUK; g += 256) { r[g] = 0; base_[g] = (g < NBUK) ? Hs[(size_t)g * NC + c] : 0; }
    __syncthreads();
    const long cb = (long)c * CHUNK;
#pragma unroll 2
    for (int it = 0; it < CHUNK / 256; ++it) {
        long e = cb + it * 256 + t;
        if (e < E) {
            unsigned d = (unsigned)dst[e];
            int g = d >> 8;
            int pos = base_[g] + atomicAdd(&r[g], 1);
            uint2 p = {d, (unsigned)src[e]};
            tmp[pos] = p;
        }
    }
}

// ---------------- per-bucket fine histogram -> per-node counts (coalesced) ----------------
__global__ __launch_bounds__(256) void hist2(const uint2* __restrict__ tmp,
                                             const int* __restrict__ Hs,
                                             int* __restrict__ cnt, int NC) {
    __shared__ int h[256];
    const int t = threadIdx.x, b = blockIdx.x;
    h[t] = 0;
    __syncthreads();
    const int beg = Hs[(size_t)b * NC], end = Hs[(size_t)(b + 1) * NC];
    for (int e = beg + t; e < end; e += 256) atomicAdd(&h[tmp[e].x & 255u], 1);
    __syncthreads();
    const int d = b * 256 + t;
    if (d < N_NODES) cnt[d] = h[t];
}

__global__ void inv_from_cnt(const int* __restrict__ cnt, float* __restrict__ invd, int n) {
    int i = blockIdx.x * blockDim.x + threadIdx.x;
    if (i < n) invd[i] = 1.0f / (float)max(cnt[i], 1);
}

// ---------------- per-bucket scatter into csr (contiguous region per block) ----------------
__global__ __launch_bounds__(256) void scatter2(const uint2* __restrict__ tmp,
                                                const int* __restrict__ Hs,
                                                const int* __restrict__ roff,
                                                int* __restrict__ csr, int NC) {
    __shared__ int cur[256];
    const int t = threadIdx.x, b = blockIdx.x;
    const int d = b * 256 + t;
    cur[t] = (d <= N_NODES) ? roff[min(d, N_NODES)] : 0;
    __syncthreads();
    const int beg = Hs[(size_t)b * NC], end = Hs[(size_t)(b + 1) * NC];
    for (int e = beg + t; e < end; e += 256) {
        uint2 p = tmp[e];
        int pos = atomicAdd(&cur[p.x & 255u], 1);
        csr[pos] = (int)p.y;
    }
}

// ---------------- round f32 -> bf16 ----------------
__global__ void round_bf16(const float* __restrict__ x, ushort_t* __restrict__ xb, long n) {
    long i = ((long)blockIdx.x * blockDim.x + threadIdx.x) * 4;
    if (i < n) {
        float4 v = *(const float4*)(x + i);
        ushort4 o = {f2bfbits(v.x), f2bfbits(v.y), f2bfbits(v.z), f2bfbits(v.w)};
        *(ushort4*)(xb + i) = o;
    }
}

// ---------------- weight cvt + transpose ----------------
__global__ void cvt_transpose(const float* __restrict__ W, ushort_t* __restrict__ WT,
                              int K, int J, int kdst0, int ldwt) {
    int idx = blockIdx.x * blockDim.x + threadIdx.x;
    if (idx >= K * J) return;
    int k = idx / J, j = idx - k * J;
    WT[(size_t)j * ldwt + kdst0 + k] = f2bfbits(W[idx]);
}

// ---------------- gather-mean: one wave/node, 4 groups x 16 lanes, 4x unroll ----------------
template <typename OT>
__global__ __launch_bounds__(256) void gather_mean(const ushort_t* __restrict__ Y,
                                                   const int* __restrict__ roff,
                                                   const int* __restrict__ csr,
                                                   const float* __restrict__ invd,
                                                   OT* __restrict__ out, int out_ld, int col0) {
    const int w = (blockIdx.x * blockDim.x + threadIdx.x) >> 6;  // node
    if (w >= N_NODES) return;
    const int lane = threadIdx.x & 63;
    const int g = lane >> 4;        // edge group 0..3
    const int l = lane & 15;        // 16B chunk within row
    const int e0 = roff[w], e1 = roff[w + 1];

    float a[8] = {0.f, 0.f, 0.f, 0.f, 0.f, 0.f, 0.f, 0.f};

    int e = e0 + g;
    for (; e + 12 < e1; e += 16) {
        const int s0 = csr[e], s1 = csr[e + 4], s2 = csr[e + 8], s3 = csr[e + 12];
        uint4 u0 = *(const uint4*)(Y + (size_t)s0 * 128 + l * 8);
        uint4 u1 = *(const uint4*)(Y + (size_t)s1 * 128 + l * 8);
        uint4 u2 = *(const uint4*)(Y + (size_t)s2 * 128 + l * 8);
        uint4 u3 = *(const uint4*)(Y + (size_t)s3 * 128 + l * 8);
        acc8(a, u0); acc8(a, u1); acc8(a, u2); acc8(a, u3);
    }
    for (; e < e1; e += 4) {
        const int s0 = csr[e];
        uint4 u0 = *(const uint4*)(Y + (size_t)s0 * 128 + l * 8);
        acc8(a, u0);
    }

#pragma unroll
    for (int i = 0; i < 8; ++i) {
        a[i] += __shfl_xor(a[i], 16);
        a[i] += __shfl_xor(a[i], 32);
    }

    if (g != 0) return;
    const float iv = invd[w];
#pragma unroll
    for (int i = 0; i < 8; ++i) a[i] *= iv;

    if constexpr (sizeof(OT) == 4) {
        float* op = (float*)out + (size_t)w * out_ld + col0 + l * 8;
        float4 s0 = {a[0], a[1], a[2], a[3]};
        float4 s1 = {a[4], a[5], a[6], a[7]};
        *(float4*)op = s0;
        *(float4*)(op + 4) = s1;
    } else {
        ushort_t* op = (ushort_t*)out + (size_t)w * out_ld + col0 + l * 8;
        ushort4 lohi0 = {f2bfbits(a[0]), f2bfbits(a[1]), f2bfbits(a[2]), f2bfbits(a[3])};
        ushort4 lohi1 = {f2bfbits(a[4]), f2bfbits(a[5]), f2bfbits(a[6]), f2bfbits(a[7])};
        *(ushort4*)op = lohi0;
        *(ushort4*)(op + 4) = lohi1;
    }
}

// ---------------- MFMA GEMM: 128x128 tile, BK=64, 4 waves, 16x16x32 bf16 ----------------
template <int KH, bool CONCAT, bool EPI, bool BR, typename OT>
__global__ __launch_bounds__(256) void mfma_gemm(const ushort_t* __restrict__ A,
                                                 const ushort_t* __restrict__ A2,
                                                 const ushort_t* __restrict__ WT,
                                                 const float* __restrict__ bias,
                                                 OT* __restrict__ out, int out_ld,
                                                 int jrow0, int oc0) {
    constexpr int KTOT = CONCAT ? 2 * KH : KH;
    constexpr int BK = 64;
    __shared__ ushort_t smem[16384];
    ushort_t* As = smem;
    ushort_t* Bs = smem + 8192;

    const int tid = threadIdx.x;
    const int lane = tid & 63;
    const int w = tid >> 6;
    const int wr = w >> 1, wc = w & 1;
    const int n0 = blockIdx.x * 128;
    const int wcolbase = jrow0 + blockIdx.y * 128;
    const int ocolbase = oc0 + blockIdx.y * 128;

    const int srow = lane >> 3;
    const int skc = (lane & 7) ^ srow;

    f32x4 acc[4][4];
#pragma unroll
    for (int m = 0; m < 4; ++m)
#pragma unroll
        for (int n = 0; n < 4; ++n) acc[m][n] = (f32x4){0.f, 0.f, 0.f, 0.f};

    for (int k0 = 0; k0 < KTOT; k0 += BK) {
        const ushort_t* Asrc = A;
        int ak = k0;
        if (CONCAT && k0 >= KH) { Asrc = A2; ak = k0 - KH; }
#pragma unroll
        for (int i = 0; i < 4; ++i) {
            const int ci = w * 4 + i;
            int grow = n0 + ci * 8 + srow;
            grow = min(grow, N_NODES - 1);
            const ushort_t* g = Asrc + (size_t)grow * KH + ak + skc * 8;
            __builtin_amdgcn_global_load_lds((const unsigned int*)g,
                                             (unsigned int*)(As + ci * 512), 16, 0, 0);
        }
#pragma unroll
        for (int i = 0; i < 4; ++i) {
            const int ci = w * 4 + i;
            const int jrow = wcolbase + ci * 8 + srow;
            const ushort_t* g = WT + (size_t)jrow * KTOT + k0 + skc * 8;
            __builtin_amdgcn_global_load_lds((const unsigned int*)g,
                                             (unsigned int*)(Bs + ci * 512), 16, 0, 0);
        }
        __syncthreads();

#pragma unroll
        for (int kk = 0; kk < 2; ++kk) {
            const int kc = kk * 4 + (lane >> 4);
            bf16x8 af[4], bf[4];
#pragma unroll
            for (int m = 0; m < 4; ++m) {
                const int row = wr * 64 + m * 16 + (lane & 15);
                af[m] = *(const bf16x8*)((const char*)As + row * 128 + ((kc ^ (row & 7)) << 4));
            }
#pragma unroll
            for (int n = 0; n < 4; ++n) {
                const int row = wc * 64 + n * 16 + (lane & 15);
                bf[n] = *(const bf16x8*)((const char*)Bs + row * 128 + ((kc ^ (row & 7)) << 4));
            }
#pragma unroll
            for (int m = 0; m < 4; ++m)
#pragma unroll
                for (int n = 0; n < 4; ++n)
                    acc[m][n] = __builtin_amdgcn_mfma_f32_16x16x32_bf16(af[m], bf[n],
                                                                        acc[m][n], 0, 0, 0);
        }
        __syncthreads();
    }

    const int c15 = lane & 15;
    const int r4 = (lane >> 4) * 4;
#pragma unroll
    for (int m = 0; m < 4; ++m) {
#pragma unroll
        for (int q = 0; q < 4; ++q) {
            const int row_g = n0 + wr * 64 + m * 16 + r4 + q;
            if (row_g >= N_NODES) continue;
#pragma unroll
            for (int n = 0; n < 4; ++n) {
                const int lcol = wc * 64 + n * 16 + c15;
                float v = acc[m][n][q];
                OT* op = out + (size_t)row_g * out_ld + ocolbase + lcol;
                if constexpr (EPI) {
                    if constexpr (sizeof(OT) == 4) v += *(const float*)op;
                    else v += bfbits2f(*(const ushort_t*)op);
                }
                if constexpr (BR) v = fmaxf(v + bias[wcolbase + lcol], 0.0f);
                if constexpr (sizeof(OT) == 4) *(float*)op = v;
                else *(ushort_t*)op = f2bfbits(v);
            }
        }
    }
}

// ---------------- launch ----------------
extern "C" void kernel_launch(void* const* d_in, const int* in_sizes, int n_in,
                              void* d_out, int out_size, void* d_ws, size_t ws_size,
                              hipStream_t stream) {
    const float* x   = (const float*)d_in[0];
    const int*   ei  = (const int*)d_in[1];
    const float* Wl1 = (const float*)d_in[2];
    const float* Wr1 = (const float*)d_in[3];
    const float* b1  = (const float*)d_in[4];
    const float* Wl2 = (const float*)d_in[5];
    const float* Wr2 = (const float*)d_in[6];
    const float* b2  = (const float*)d_in[7];
    const float* Wl3 = (const float*)d_in[8];
    const float* Wr3 = (const float*)d_in[9];
    const float* b3  = (const float*)d_in[10];

    const int E = in_sizes[1] / 2;
    const int* src = ei;
    const int* dst = ei + E;
    const int N = N_NODES;
    const int NC = (E + CHUNK - 1) / CHUNK;       // chunks (98 @ 1.6M)
    const int nH = NBUK * NC;                      // hist entries (38318)

    // ---- workspace arena (149.1 MB; 154.6 MB proven available in round 2) ----
    char* ws = (char*)d_ws;
    float* invd = (float*)(ws + 0);                  // 400,000
    int* cnt    = (int*)(ws + 400000);               // 400,000
    int* roff   = (int*)(ws + 800000);               // 400,016 (N+1, padded)
    int* bsum   = (int*)(ws + 1200016);              // 1,024
    int* H      = (int*)(ws + 1201040);              // (NBUK*NC+1)*4 <= 153,280
    ushort_t* WT1  = (ushort_t*)(ws + 1354320);      // 131,072
    ushort_t* WT2l = (ushort_t*)(ws + 1485392);      // 131,072
    ushort_t* WT2r = (ushort_t*)(ws + 1616464);      // 131,072
    ushort_t* WT3l = (ushort_t*)(ws + 1747536);      // 65,536
    ushort_t* WT3r = (ushort_t*)(ws + 1813072);      // 65,536
    uint2* tmp  = (uint2*)(ws + 1878608);            // 12,800,000
    int* csr    = (int*)(ws + 14678608);             // 6,400,000
    ushort_t* h1 = (ushort_t*)(ws + 21078608);       // 51,200,000
    ushort_t* h2 = (ushort_t*)(ws + 72278608);       // 51,200,000
    ushort_t* M1 = h2;                                // alias (h2 dead during L1)
    ushort_t* T1 = (ushort_t*)(ws + 123478608);      // 25,600,000
    const size_t WS_NEED = 149078608;
    if (ws_size < WS_NEED) return;

    const int GX = (N + 127) / 128;   // 782
    const int NBH = (nH + 1023) / 1024;  // scan blocks for H (38)
    const int NBN = (N + 1023) / 1024;   // scan blocks for cnt (98)

    // ---- CSR build: atomic-free two-level bucket sort ----
    hist1<<<NC, 256, 0, stream>>>(dst, H, E, NC);
    scan1<<<NBH, 256, 0, stream>>>(H, H, bsum, nH);
    scan2<<<1, 256, 0, stream>>>(bsum, NBH);
    scan3<<<(nH + 256) / 256, 256, 0, stream>>>(H, bsum, nH, E);   // H[nH] = E
    binA<<<NC, 256, 0, stream>>>(src, dst, H, tmp, E, NC);
    hist2<<<NBUK, 256, 0, stream>>>(tmp, H, cnt, NC);
    inv_from_cnt<<<(N + 255) / 256, 256, 0, stream>>>(cnt, invd, N);
    scan1<<<NBN, 256, 0, stream>>>(cnt, roff, bsum, N);
    scan2<<<1, 256, 0, stream>>>(bsum, NBN);
    scan3<<<(N + 256) / 256, 256, 0, stream>>>(roff, bsum, N, E);  // roff[N] = E
    scatter2<<<NBUK, 256, 0, stream>>>(tmp, H, roff, csr, NC);

    // ---- weight prep ----
    cvt_transpose<<<(128 * 256 + 255) / 256, 256, 0, stream>>>(Wl1, WT1, 128, 256, 0, 256);
    cvt_transpose<<<(128 * 256 + 255) / 256, 256, 0, stream>>>(Wr1, WT1, 128, 256, 128, 256);
    cvt_transpose<<<(256 * 256 + 255) / 256, 256, 0, stream>>>(Wl2, WT2l, 256, 256, 0, 256);
    cvt_transpose<<<(256 * 256 + 255) / 256, 256, 0, stream>>>(Wr2, WT2r, 256, 256, 0, 256);
    cvt_transpose<<<(256 * 128 + 255) / 256, 256, 0, stream>>>(Wl3, WT3l, 256, 128, 0, 256);
    cvt_transpose<<<(256 * 128 + 255) / 256, 256, 0, stream>>>(Wr3, WT3r, 256, 128, 0, 256);

    // ---- layer 1 ----
    round_bf16<<<(N * 128 / 4 + 255) / 256, 256, 0, stream>>>(x, T1, (long)N * 128);
    gather_mean<ushort_t><<<(N * 64 + 255) / 256, 256, 0, stream>>>(
        T1, roff, csr, invd, M1, 128, 0);
    mfma_gemm<128, true, false, true, ushort_t><<<dim3(GX, 2), 256, 0, stream>>>(
        M1, T1, WT1, b1, h1, 256, 0, 0);

    // ---- layer 2 ----
    for (int c = 0; c < 256; c += 128) {
        mfma_gemm<256, false, false, false, ushort_t><<<dim3(GX, 1), 256, 0, stream>>>(
            h1, nullptr, WT2l, nullptr, T1, 128, c, 0);
        gather_mean<ushort_t><<<(N * 64 + 255) / 256, 256, 0, stream>>>(
            T1, roff, csr, invd, h2, 256, c);
        mfma_gemm<256, false, true, true, ushort_t><<<dim3(GX, 1), 256, 0, stream>>>(
            h1, nullptr, WT2r, b2, h2, 256, c, c);
    }

    // ---- layer 3 ----
    mfma_gemm<256, false, false, false, ushort_t><<<dim3(GX, 1), 256, 0, stream>>>(
        h2, nullptr, WT3l, nullptr, T1, 128, 0, 0);
    gather_mean<float><<<(N * 64 + 255) / 256, 256, 0, stream>>>(
        T1, roff, csr, invd, (float*)d_out, 128, 0);
    mfma_gemm<256, false, true, true, float><<<dim3(GX, 1), 256, 0, stream>>>(
        h2, nullptr, WT3r, b3, (float*)d_out, 128, 0, 0);
}